// Round 17
// baseline (616.199 us; speedup 1.0000x reference)
//
#include <hip/hip_runtime.h>

typedef unsigned short u16;
typedef unsigned int u32;
typedef __bf16 bf16x8 __attribute__((ext_vector_type(8)));
typedef float f32x4 __attribute__((ext_vector_type(4)));
typedef u32 u32x4 __attribute__((ext_vector_type(4)));

__device__ __forceinline__ u16 f2bf(float f) {
  u32 u = __builtin_bit_cast(u32, f);
  return (u16)((u + 0x7fffu + ((u >> 16) & 1u)) >> 16);  // RNE
}

__device__ __forceinline__ f32x4 mfma16(bf16x8 a, bf16x8 b, f32x4 c) {
  return __builtin_amdgcn_mfma_f32_16x16x32_bf16(a, b, c, 0, 0, 0);
}

__device__ __forceinline__ u32 cvtpk_bf16(float lo, float hi) {
  u32 r;
  asm("v_cvt_pk_bf16_f32 %0, %1, %2" : "=v"(r) : "v"(lo), "v"(hi));
  return r;
}

__device__ __forceinline__ float fexp2(float x) {   // raw v_exp_f32 (2^x)
  float r;
  asm("v_exp_f32 %0, %1" : "=v"(r) : "v"(x));
  return r;
}

struct alignas(8) U16x4 { u16 x, y, z, w; };

#define AS1 __attribute__((address_space(1)))
#define AS3 __attribute__((address_space(3)))
// async global->LDS, 16B per lane; lds dest = wave-uniform base + lane*16
__device__ __forceinline__ void gl16(const u16* g, u16* l) {
  __builtin_amdgcn_global_load_lds((const AS1 u32*)g, (AS3 u32*)l, 16, 0, 0);
}

// ---------- fused prep: x fp32->bf16 convert + both weight transposes ----------
__device__ __forceinline__ void transpose_tile(const float* __restrict__ in,
                                               u16* __restrict__ out,
                                               int rows, int cols, int bx, int by,
                                               int tidx) {
  __shared__ float tile[64][65];
  int bc = bx * 64, br = by * 64;
  int tx = tidx & 15;   // float4-col / row-quad index
  int ty = tidx >> 4;   // 0..15
#pragma unroll
  for (int i = 0; i < 4; ++i) {
    int r = ty + i * 16;
    float4 v = *(const float4*)&in[(long)(br + r) * cols + bc + tx * 4];
    tile[r][tx * 4 + 0] = v.x;
    tile[r][tx * 4 + 1] = v.y;
    tile[r][tx * 4 + 2] = v.z;
    tile[r][tx * 4 + 3] = v.w;
  }
  __syncthreads();
#pragma unroll
  for (int i = 0; i < 4; ++i) {
    int c = ty + i * 16;
    int r4 = tx * 4;
    U16x4 o{f2bf(tile[r4 + 0][c]), f2bf(tile[r4 + 1][c]),
            f2bf(tile[r4 + 2][c]), f2bf(tile[r4 + 3][c])};
    *(U16x4*)&out[(long)(bc + c) * rows + br + r4] = o;
  }
}

__global__ __launch_bounds__(256) void k_prep(const float* __restrict__ x,
                                              u16* __restrict__ xb,
                                              const float* __restrict__ wqkv,
                                              u16* __restrict__ wqt,
                                              const float* __restrict__ wproj,
                                              u16* __restrict__ wpt) {
  int bid = blockIdx.x;
  int tid = threadIdx.x;
  if (bid < 2048) {
    long n4 = (8192L * 2048) / 4;
    long i = (long)bid * 256 + tid;
    long stride = 2048L * 256;
    for (; i < n4; i += stride) {
      float4 v = ((const float4*)x)[i];
      U16x4 o{f2bf(v.x), f2bf(v.y), f2bf(v.z), f2bf(v.w)};
      ((U16x4*)xb)[i] = o;
    }
  } else if (bid < 5120) {
    int idx = bid - 2048;                      // 96 x 32 tiles
    transpose_tile(wqkv, wqt, 2048, 6144, idx % 96, idx / 96, tid);
  } else {
    int idx = bid - 5120;                      // 32 x 32 tiles
    transpose_tile(wproj, wpt, 2048, 2048, idx % 32, idx / 32, tid);
  }
}

// ------------- GEMM 256x256: C[M][N] = A[M][K](bf16) @ Bt[N][K](bf16)^T -------------
// R6-exact K-loop (measured 9x: 185-189us GEMM1, MfmaUtil 50-52%, 0 conflicts).
// Failed refinements, do not retry: R7 coarse 2-phase split (-29%, m196);
// R10 ping-pong register prefetch (-30%); R17 paper-rederivation of the 8-phase
// ledger converges to R7's structure -> frozen.
// WRITE_VT epilogue (R14, verified): V-region blocks (bcol>=4096) write
// transposed directly to Vt[bh][d][t], replacing k_transpose_v.
template <typename OutT, bool WRITE_VT>
__global__ __launch_bounds__(512, 2) void k_gemm256(const u16* __restrict__ A,
                                                    const u16* __restrict__ Bt,
                                                    OutT* __restrict__ C,
                                                    u16* __restrict__ vt,
                                                    int M, int N, int K) {
  __shared__ alignas(16) u16 As[4][8192];  // 4 x 16KB
  __shared__ alignas(16) u16 Bs[4][8192];  // 4 x 16KB  (total 128KB)

  int gx = gridDim.x;
  int nwg = gx * gridDim.y;
  int bid = blockIdx.y * gx + blockIdx.x;
  int swz = (bid & 7) * (nwg >> 3) + (bid >> 3);
  int rem = swz % (gx * 4);
  int bx = rem >> 2;
  int by = (swz / (gx * 4)) * 4 + (rem & 3);

  int tid = threadIdx.x;
  int lane = tid & 63;
  int w = tid >> 6;
  int wr = w >> 2, wc = w & 3;     // wave tile: rows wr*128+[0,128), cols wc*64+[0,64)
  int lr = lane & 15, lg = lane >> 4;
  long brow = (long)by * 256, bcol = (long)bx * 256;

  int rS[2], cS[2];
#pragma unroll
  for (int i = 0; i < 2; ++i) {
    int q = i * 512 + tid;
    rS[i] = q >> 2;                                 // tile row (0..255)
    cS[i] = ((q & 3) ^ ((rS[i] >> 1) & 3)) << 3;    // swizzled source k-chunk (u16 off)
  }
  const u16* Ab = A + brow * K;
  const u16* Bb = Bt + bcol * K;

  int offA[8], offB[4];
#pragma unroll
  for (int m = 0; m < 8; ++m) {
    int row = wr * 128 + m * 16 + lr;
    offA[m] = row * 32 + ((lg ^ ((row >> 1) & 3)) << 3);
  }
#pragma unroll
  for (int n = 0; n < 4; ++n) {
    int row = wc * 64 + n * 16 + lr;
    offB[n] = row * 32 + ((lg ^ ((row >> 1) & 3)) << 3);
  }

  f32x4 zero = {0.f, 0.f, 0.f, 0.f};
  f32x4 acc[8][4];
#pragma unroll
  for (int m = 0; m < 8; ++m)
#pragma unroll
    for (int n = 0; n < 4; ++n) acc[m][n] = zero;

  int NS = K >> 5;  // K-steps (64 for K=2048)

#define STAGE256(SBUF, KT)                                                          \
  do {                                                                              \
    int kk_ = (KT) << 5;                                                            \
    gl16(Ab + (long)rS[0] * K + kk_ + cS[0], &As[SBUF][(0 * 512 + w * 64) * 8]);    \
    gl16(Ab + (long)rS[1] * K + kk_ + cS[1], &As[SBUF][(1 * 512 + w * 64) * 8]);    \
    gl16(Bb + (long)rS[0] * K + kk_ + cS[0], &Bs[SBUF][(0 * 512 + w * 64) * 8]);    \
    gl16(Bb + (long)rS[1] * K + kk_ + cS[1], &Bs[SBUF][(1 * 512 + w * 64) * 8]);    \
  } while (0)

  STAGE256(0, 0);
  STAGE256(1, 1);
  STAGE256(2, 2);
  asm volatile("s_waitcnt vmcnt(8)" ::: "memory");
  __builtin_amdgcn_s_barrier();

  for (int s = 0; s < NS; ++s) {
    int cb = s & 3;
    bf16x8 af[8], bfn[4];
#pragma unroll
    for (int m = 0; m < 8; ++m) af[m] = *(const bf16x8*)&As[cb][offA[m]];
#pragma unroll
    for (int n = 0; n < 4; ++n) bfn[n] = *(const bf16x8*)&Bs[cb][offB[n]];
    int t = s + 3;
    int tb = t & 3;
    if (t > NS - 1) t = NS - 1;
    STAGE256(tb, t);
    __builtin_amdgcn_s_setprio(1);
#pragma unroll
    for (int m = 0; m < 4; ++m)
#pragma unroll
      for (int n = 0; n < 4; ++n) acc[m][n] = mfma16(af[m], bfn[n], acc[m][n]);
    __builtin_amdgcn_s_setprio(0);
    __builtin_amdgcn_s_setprio(1);
#pragma unroll
    for (int m = 4; m < 8; ++m)
#pragma unroll
      for (int n = 0; n < 4; ++n) acc[m][n] = mfma16(af[m], bfn[n], acc[m][n]);
    __builtin_amdgcn_s_setprio(0);
    asm volatile("s_waitcnt vmcnt(8)" ::: "memory");
    __builtin_amdgcn_s_barrier();
  }
#undef STAGE256
  asm volatile("s_waitcnt vmcnt(0)" ::: "memory");

  // C/D layout: col = lane&15, row = (lane>>4)*4 + reg   [measured m89/m91]
  if constexpr (WRITE_VT) {
    if (bcol >= 4096) {
      // V-region block: write transposed to Vt[(b*16+h)*128 + d][t]
      int b_ = (int)(brow >> 11);
      int tb_ = (int)(brow & 2047) + wr * 128;
#pragma unroll
      for (int m = 0; m < 8; ++m)
#pragma unroll
        for (int n = 0; n < 4; ++n) {
          int hd = (int)(bcol - 4096) + wc * 64 + n * 16 + lr;
          int h_ = hd >> 7, d_ = hd & 127;
          U16x4 pk{f2bf(acc[m][n][0]), f2bf(acc[m][n][1]),
                   f2bf(acc[m][n][2]), f2bf(acc[m][n][3])};
          *(U16x4*)(vt + ((long)(b_ * 16 + h_) * 128 + d_) * 2048 + tb_ + m * 16 + lg * 4) = pk;
        }
      return;
    }
  }
#pragma unroll
  for (int m = 0; m < 8; ++m)
#pragma unroll
    for (int n = 0; n < 4; ++n)
#pragma unroll
      for (int r = 0; r < 4; ++r) {
        long row = brow + wr * 128 + m * 16 + lg * 4 + r;
        long col = bcol + wc * 64 + n * 16 + lr;
        float v = acc[m][n][r];
        if constexpr (sizeof(OutT) == 2)
          C[row * N + col] = (OutT)f2bf(v);
        else
          C[row * N + col] = v;
      }
}

// ------------- flash attention v10: kv-tile 32, 3 blocks/CU (occupancy) -------
// QKV: [8192][6144] bf16 (V third unused); Vt: [64][128][2048] bf16; Y: [8192][2048]
// Grid: x = bh (64), y = 16 (qb = 15 - y). LDS 32KB -> 3 blocks/CU = 12 waves
// (was 2 blocks / 8 waves at kv64): +50% latency hiding for the QK->SM->PV chain.
// Counted-vmcnt ledger (never 0): prologue vmcnt(2); per tile: stage K(t+1)[2],
// QK(t), stage V(t+1)[2], vmcnt(4)+barrier (own V(t) landed), PV(t),
// vmcnt(2)+barrier (own K(t+1) landed; V(t+1) stays in flight).
// Do NOT: 8-wave blocks (R9 +23us), setprio/THR=8 defer-max (R8 +29us, m190).
__global__ __launch_bounds__(256, 3) void k_attn2(const u16* __restrict__ qkv,
                                                  const u16* __restrict__ vt,
                                                  u16* __restrict__ y) {
  __shared__ alignas(16) u16 Ks[2][32 * 128];   // [t row][chunk-swizzled d], 8KB each
  __shared__ alignas(16) u16 Vs[2][128 * 32];   // [d row][chunk-swizzled t], 8KB each

  int bh = blockIdx.x;
  int qb = 15 - (int)blockIdx.y;
  int b = bh >> 4, h = bh & 15;
  int tid = threadIdx.x;
  int lane = tid & 63;
  int w = tid >> 6;
  int lr = lane & 15, lg = lane >> 4;
  int x7 = lr & 7;
  bool hiA = (lane & 32) != 0;   // lg >= 2
  bool hiB = (lane & 16) != 0;   // lg odd
  const float scale2 = 0.08838834764831845f * 1.4426950408889634f;  // /sqrt(128) * log2e

  const u16* kbase = qkv + (long)(b * 2048) * 6144 + 2048 + h * 128;
  const u16* vtbh = vt + (long)bh * 128 * 2048;
  int qbase = qb * 128 + w * 32;

  // Q fragments (B-operand of swapped QK^T): lane lr = q row, lg = d-subgroup
  const u16* qptr = qkv + (long)(qb * 128 + b * 2048) * 6144 + h * 128;
  bf16x8 qf[2][4];
  for (int qsub = 0; qsub < 2; ++qsub)
    for (int dc = 0; dc < 4; ++dc)
      qf[qsub][dc] = *(const bf16x8*)(qptr + (long)(w * 32 + qsub * 16 + lr) * 6144 + dc * 32 + lg * 8);

  f32x4 zero = {0.f, 0.f, 0.f, 0.f};
  f32x4 o[2][8];
  for (int qs = 0; qs < 2; ++qs)
    for (int ds = 0; ds < 8; ++ds) o[qs][ds] = zero;
  float m_run[2] = {-1e30f, -1e30f};   // log2 domain
  float l_run[2] = {0.f, 0.f};

  int nkt = 4 * qb + 4;
  int qmaxw = qbase + 31;

// K tile: 32 rows x 128 d (8KB). 2 gl16/wave: rl_ = w*8+i*4, 4 rows per gl16
// (16 lanes/row), layout chunk = lane&15, content chunk = (lane&15)^(row&7).
#define STAGE_K(BUF, KT)                                                        \
  do {                                                                          \
    for (int i_ = 0; i_ < 2; ++i_) {                                            \
      int rl_ = w * 8 + i_ * 4;                                                 \
      int row_ = rl_ + (lane >> 4);                                             \
      int ch_ = (lane & 15) ^ (row_ & 7);                                       \
      gl16(kbase + (long)((KT)*32 + row_) * 6144 + ch_ * 8, &Ks[BUF][rl_ * 128]); \
    }                                                                           \
  } while (0)

// V tile: 128 d x 32 t (8KB). 2 gl16/wave: dl_ = w*32+i*16, 16 d-rows per gl16
// (4 lanes/row), layout chunk = lane&3, content chunk = (lane&3)^((d>>1)&3).
#define STAGE_V(BUF, KT)                                                        \
  do {                                                                          \
    for (int i_ = 0; i_ < 2; ++i_) {                                            \
      int dl_ = w * 32 + i_ * 16;                                               \
      int d_ = dl_ + (lane >> 2);                                               \
      int ch_ = (lane & 3) ^ ((d_ >> 1) & 3);                                   \
      gl16(vtbh + (long)d_ * 2048 + (KT)*32 + ch_ * 8, &Vs[BUF][dl_ * 32]);     \
    }                                                                           \
  } while (0)

// MASKED is a 0/1 literal -> dead branch folds at compile time
#define QKPART(BUF, KT, PA, MASKED)                                             \
  do {                                                                          \
    const u16* Kb = &Ks[BUF][0];                                                \
    f32x4 s[2][2];                                                              \
    for (int qs = 0; qs < 2; ++qs)                                              \
      for (int ks = 0; ks < 2; ++ks) s[qs][ks] = zero;                          \
    for (int ks = 0; ks < 2; ++ks) {                                            \
      int row = ks * 16 + lr;                                                   \
      for (int dc = 0; dc < 4; ++dc) {                                          \
        bf16x8 kf = *(const bf16x8*)(Kb + row * 128 + ((dc * 4 + lg) ^ x7) * 8); \
        s[0][ks] = mfma16(kf, qf[0][dc], s[0][ks]);                             \
        s[1][ks] = mfma16(kf, qf[1][dc], s[1][ks]);                             \
      }                                                                         \
    }                                                                           \
    for (int qs = 0; qs < 2; ++qs) {                                            \
      int qg = qbase + qs * 16 + lr;                                            \
      float p[8];                                                               \
      float tmax = -1e30f;                                                      \
      for (int ks = 0; ks < 2; ++ks)                                            \
        for (int r = 0; r < 4; ++r) {                                           \
          float v = s[qs][ks][r] * scale2;                                      \
          if (MASKED) {                                                         \
            int key = (KT)*32 + ks * 16 + lg * 4 + r;                           \
            v = (key <= qg) ? v : -1e30f;                                       \
          }                                                                     \
          p[ks * 4 + r] = v;                                                    \
          tmax = fmaxf(tmax, v);                                                \
        }                                                                       \
      tmax = fmaxf(tmax, __shfl_xor(tmax, 16));                                 \
      tmax = fmaxf(tmax, __shfl_xor(tmax, 32));                                 \
      /* exact rescale-skip: if tmax <= m_run wave-wide, alpha == 1 exactly */  \
      bool noresc = (__all(tmax <= m_run[qs]) != 0);                            \
      float m_new = noresc ? m_run[qs] : fmaxf(m_run[qs], tmax);                \
      float psum = 0.f;                                                         \
      for (int i = 0; i < 8; ++i) {                                             \
        p[i] = fexp2(p[i] - m_new);                                             \
        psum += p[i];                                                           \
      }                                                                         \
      psum += __shfl_xor(psum, 16);                                             \
      psum += __shfl_xor(psum, 32);                                             \
      if (noresc) {                                                             \
        l_run[qs] = l_run[qs] + psum;                                           \
      } else {                                                                  \
        float alpha = fexp2(m_run[qs] - m_new);                                 \
        l_run[qs] = l_run[qs] * alpha + psum;                                   \
        m_run[qs] = m_new;                                                      \
        float alr[4];                                                           \
        for (int r = 0; r < 4; ++r) alr[r] = __shfl(alpha, lg * 4 + r);         \
        for (int ds = 0; ds < 8; ++ds)                                          \
          for (int r = 0; r < 4; ++r) o[qs][ds][r] *= alr[r];                   \
      }                                                                         \
      /* in-register P regroup (verified R11), single 32-key group */           \
      {                                                                         \
        u32 w0 = cvtpk_bf16(p[0], p[1]);                                        \
        u32 w1 = cvtpk_bf16(p[2], p[3]);                                        \
        u32 w2 = cvtpk_bf16(p[4], p[5]);                                        \
        u32 w3 = cvtpk_bf16(p[6], p[7]);                                        \
        u32 a0 = hiA ? w0 : w2, a1 = hiA ? w1 : w3;                             \
        u32 r0 = __shfl_xor(a0, 32), r1 = __shfl_xor(a1, 32);                   \
        u32 q0 = hiA ? r0 : w0, q1 = hiA ? r1 : w1;                             \
        u32 q2 = hiA ? w2 : r0, q3 = hiA ? w3 : r1;                             \
        u32 s0 = hiB ? q0 : q2, s1 = hiB ? q1 : q3;                             \
        u32 t0 = __shfl_xor(s0, 16), t1 = __shfl_xor(s1, 16);                   \
        u32x4 fw;                                                               \
        fw[0] = hiB ? t0 : q0;                                                  \
        fw[1] = hiB ? t1 : q1;                                                  \
        fw[2] = hiB ? q2 : t0;                                                  \
        fw[3] = hiB ? q3 : t1;                                                  \
        PA[qs] = __builtin_bit_cast(bf16x8, fw);                                \
      }                                                                         \
    }                                                                           \
  } while (0)

#define PVPART(BUF, PA)                                                         \
  do {                                                                          \
    const u16* Vb = &Vs[BUF][0];                                                \
    int chv = (lg ^ ((lr >> 1) & 3)) << 3;                                      \
    for (int ds = 0; ds < 8; ++ds) {                                            \
      bf16x8 vf = *(const bf16x8*)(Vb + (ds * 16 + lr) * 32 + chv);             \
      o[0][ds] = mfma16(PA[0], vf, o[0][ds]);                                   \
      o[1][ds] = mfma16(PA[1], vf, o[1][ds]);                                   \
    }                                                                           \
  } while (0)

  // prologue: K(0),V(0) staged (4 loads); vmcnt(2) -> K(0) landed (own),
  // barrier -> cross-wave; V(0)'s 2 loads stay in flight (steady-state counts).
  STAGE_K(0, 0);
  STAGE_V(0, 0);
  asm volatile("s_waitcnt vmcnt(2)" ::: "memory");
  __builtin_amdgcn_s_barrier();

  for (int t = 0; t < nkt; ++t) {
    int tn = (t + 1 < nkt) ? t + 1 : nkt - 1;   // clamped tail keeps counts uniform
    int nb = (t + 1) & 1;
    bool live = (t * 32 <= qmaxw);
    bool masked = (t >= 4 * qb);                // last 4 tiles of the block
    bf16x8 pa[2];
    STAGE_K(nb, tn);
    if (live) {
      if (masked) QKPART(t & 1, t, pa, 1);
      else        QKPART(t & 1, t, pa, 0);
    }
    STAGE_V(nb, tn);
    // own V(t) landed (oldest 2 of 6 outstanding); barrier -> cross-wave
    asm volatile("s_waitcnt vmcnt(4)" ::: "memory");
    __builtin_amdgcn_s_barrier();
    if (live) PVPART(t & 1, pa);
    // own K(t+1) landed; V(t+1) stays in flight across the barrier
    asm volatile("s_waitcnt vmcnt(2)" ::: "memory");
    __builtin_amdgcn_s_barrier();
  }
  asm volatile("s_waitcnt vmcnt(0)" ::: "memory");
#undef STAGE_K
#undef STAGE_V
#undef QKPART
#undef PVPART

  float linv[2][4];
  for (int qs = 0; qs < 2; ++qs)
    for (int r = 0; r < 4; ++r) linv[qs][r] = 1.0f / __shfl(l_run[qs], lg * 4 + r);
  u16* yb = y + (long)(b * 2048 + qb * 128 + w * 32) * 2048 + h * 128;
  for (int qs = 0; qs < 2; ++qs)
    for (int ds = 0; ds < 8; ++ds)
      for (int r = 0; r < 4; ++r)
        yb[(long)(qs * 16 + lg * 4 + r) * 2048 + ds * 16 + lr] = f2bf(o[qs][ds][r] * linv[qs][r]);
}

// ------------------------------- launch -------------------------------
extern "C" void kernel_launch(void* const* d_in, const int* in_sizes, int n_in,
                              void* d_out, int out_size, void* d_ws, size_t ws_size,
                              hipStream_t stream) {
  const float* x = (const float*)d_in[0];       // [4,2048,2048]
  const float* w_qkv = (const float*)d_in[1];   // [2048,6144]
  const float* w_proj = (const float*)d_in[2];  // [2048,2048]
  float* out = (float*)d_out;                   // [4,2048,2048] fp32

  char* ws = (char*)d_ws;
  if (ws_size < 201326592ull) return;
  u16* QKV = (u16*)(ws);
  u16* WqT = (u16*)(ws + 100663296);
  u16* WpT = (u16*)(ws + 125829120);
  u16* Xb  = (u16*)(ws + 134217728);
  u16* Vt  = (u16*)(ws + 167772160);

  k_prep<<<6144, 256, 0, stream>>>(x, Xb, w_qkv, WqT, w_proj, WpT);

  // GEMM1 writes Q,K into QKV and V directly transposed into Vt (fused transpose)
  k_gemm256<u16, true><<<dim3(24, 32), 512, 0, stream>>>(Xb, WqT, QKV, Vt, 8192, 6144, 2048);

  k_attn2<<<dim3(64, 16), 256, 0, stream>>>(QKV, Vt, Xb /* Y */);

  k_gemm256<float, false><<<dim3(8, 32), 512, 0, stream>>>(Xb, WpT, out, nullptr, 8192, 2048, 2048);
}

// Round 18
// 396.056 us; speedup vs baseline: 1.5558x; 1.5558x over previous
//
#include <hip/hip_runtime.h>

typedef unsigned short u16;
typedef unsigned int u32;
typedef __bf16 bf16x8 __attribute__((ext_vector_type(8)));
typedef float f32x4 __attribute__((ext_vector_type(4)));
typedef u32 u32x4 __attribute__((ext_vector_type(4)));

__device__ __forceinline__ u16 f2bf(float f) {
  u32 u = __builtin_bit_cast(u32, f);
  return (u16)((u + 0x7fffu + ((u >> 16) & 1u)) >> 16);  // RNE
}

__device__ __forceinline__ f32x4 mfma16(bf16x8 a, bf16x8 b, f32x4 c) {
  return __builtin_amdgcn_mfma_f32_16x16x32_bf16(a, b, c, 0, 0, 0);
}

__device__ __forceinline__ u32 cvtpk_bf16(float lo, float hi) {
  u32 r;
  asm("v_cvt_pk_bf16_f32 %0, %1, %2" : "=v"(r) : "v"(lo), "v"(hi));
  return r;
}

__device__ __forceinline__ float fexp2(float x) {   // raw v_exp_f32 (2^x)
  float r;
  asm("v_exp_f32 %0, %1" : "=v"(r) : "v"(x));
  return r;
}

struct alignas(8) U16x4 { u16 x, y, z, w; };

#define AS1 __attribute__((address_space(1)))
#define AS3 __attribute__((address_space(3)))
// async global->LDS, 16B per lane; lds dest = wave-uniform base + lane*16
__device__ __forceinline__ void gl16(const u16* g, u16* l) {
  __builtin_amdgcn_global_load_lds((const AS1 u32*)g, (AS3 u32*)l, 16, 0, 0);
}

// ---------- fused prep: x fp32->bf16 convert + both weight transposes ----------
__device__ __forceinline__ void transpose_tile(const float* __restrict__ in,
                                               u16* __restrict__ out,
                                               int rows, int cols, int bx, int by,
                                               int tidx) {
  __shared__ float tile[64][65];
  int bc = bx * 64, br = by * 64;
  int tx = tidx & 15;   // float4-col / row-quad index
  int ty = tidx >> 4;   // 0..15
#pragma unroll
  for (int i = 0; i < 4; ++i) {
    int r = ty + i * 16;
    float4 v = *(const float4*)&in[(long)(br + r) * cols + bc + tx * 4];
    tile[r][tx * 4 + 0] = v.x;
    tile[r][tx * 4 + 1] = v.y;
    tile[r][tx * 4 + 2] = v.z;
    tile[r][tx * 4 + 3] = v.w;
  }
  __syncthreads();
#pragma unroll
  for (int i = 0; i < 4; ++i) {
    int c = ty + i * 16;
    int r4 = tx * 4;
    U16x4 o{f2bf(tile[r4 + 0][c]), f2bf(tile[r4 + 1][c]),
            f2bf(tile[r4 + 2][c]), f2bf(tile[r4 + 3][c])};
    *(U16x4*)&out[(long)(bc + c) * rows + br + r4] = o;
  }
}

__global__ __launch_bounds__(256) void k_prep(const float* __restrict__ x,
                                              u16* __restrict__ xb,
                                              const float* __restrict__ wqkv,
                                              u16* __restrict__ wqt,
                                              const float* __restrict__ wproj,
                                              u16* __restrict__ wpt) {
  int bid = blockIdx.x;
  int tid = threadIdx.x;
  if (bid < 2048) {
    long n4 = (8192L * 2048) / 4;
    long i = (long)bid * 256 + tid;
    long stride = 2048L * 256;
    for (; i < n4; i += stride) {
      float4 v = ((const float4*)x)[i];
      U16x4 o{f2bf(v.x), f2bf(v.y), f2bf(v.z), f2bf(v.w)};
      ((U16x4*)xb)[i] = o;
    }
  } else if (bid < 5120) {
    int idx = bid - 2048;                      // 96 x 32 tiles
    transpose_tile(wqkv, wqt, 2048, 6144, idx % 96, idx / 96, tid);
  } else {
    int idx = bid - 5120;                      // 32 x 32 tiles
    transpose_tile(wproj, wpt, 2048, 2048, idx % 32, idx / 32, tid);
  }
}

// ------------- GEMM 256x256: C[M][N] = A[M][K](bf16) @ Bt[N][K](bf16)^T -------------
// R6-exact K-loop (measured 10x: 185-189us GEMM1, MfmaUtil 50-52%, 0 conflicts).
// Failed refinements, do not retry: R7 coarse 2-phase split (-29%, m196);
// R10 ping-pong register prefetch (-30%); 8-phase ledger rederivation (R17
// analysis) converges to R7's structure -> frozen.
// WRITE_VT epilogue (R14, verified): V-region blocks (bcol>=4096) write
// transposed directly to Vt[bh][d][t], replacing k_transpose_v.
template <typename OutT, bool WRITE_VT>
__global__ __launch_bounds__(512, 2) void k_gemm256(const u16* __restrict__ A,
                                                    const u16* __restrict__ Bt,
                                                    OutT* __restrict__ C,
                                                    u16* __restrict__ vt,
                                                    int M, int N, int K) {
  __shared__ alignas(16) u16 As[4][8192];  // 4 x 16KB
  __shared__ alignas(16) u16 Bs[4][8192];  // 4 x 16KB  (total 128KB)

  int gx = gridDim.x;
  int nwg = gx * gridDim.y;
  int bid = blockIdx.y * gx + blockIdx.x;
  int swz = (bid & 7) * (nwg >> 3) + (bid >> 3);
  int rem = swz % (gx * 4);
  int bx = rem >> 2;
  int by = (swz / (gx * 4)) * 4 + (rem & 3);

  int tid = threadIdx.x;
  int lane = tid & 63;
  int w = tid >> 6;
  int wr = w >> 2, wc = w & 3;     // wave tile: rows wr*128+[0,128), cols wc*64+[0,64)
  int lr = lane & 15, lg = lane >> 4;
  long brow = (long)by * 256, bcol = (long)bx * 256;

  int rS[2], cS[2];
#pragma unroll
  for (int i = 0; i < 2; ++i) {
    int q = i * 512 + tid;
    rS[i] = q >> 2;                                 // tile row (0..255)
    cS[i] = ((q & 3) ^ ((rS[i] >> 1) & 3)) << 3;    // swizzled source k-chunk (u16 off)
  }
  const u16* Ab = A + brow * K;
  const u16* Bb = Bt + bcol * K;

  int offA[8], offB[4];
#pragma unroll
  for (int m = 0; m < 8; ++m) {
    int row = wr * 128 + m * 16 + lr;
    offA[m] = row * 32 + ((lg ^ ((row >> 1) & 3)) << 3);
  }
#pragma unroll
  for (int n = 0; n < 4; ++n) {
    int row = wc * 64 + n * 16 + lr;
    offB[n] = row * 32 + ((lg ^ ((row >> 1) & 3)) << 3);
  }

  f32x4 zero = {0.f, 0.f, 0.f, 0.f};
  f32x4 acc[8][4];
#pragma unroll
  for (int m = 0; m < 8; ++m)
#pragma unroll
    for (int n = 0; n < 4; ++n) acc[m][n] = zero;

  int NS = K >> 5;  // K-steps (64 for K=2048)

#define STAGE256(SBUF, KT)                                                          \
  do {                                                                              \
    int kk_ = (KT) << 5;                                                            \
    gl16(Ab + (long)rS[0] * K + kk_ + cS[0], &As[SBUF][(0 * 512 + w * 64) * 8]);    \
    gl16(Ab + (long)rS[1] * K + kk_ + cS[1], &As[SBUF][(1 * 512 + w * 64) * 8]);    \
    gl16(Bb + (long)rS[0] * K + kk_ + cS[0], &Bs[SBUF][(0 * 512 + w * 64) * 8]);    \
    gl16(Bb + (long)rS[1] * K + kk_ + cS[1], &Bs[SBUF][(1 * 512 + w * 64) * 8]);    \
  } while (0)

  STAGE256(0, 0);
  STAGE256(1, 1);
  STAGE256(2, 2);
  asm volatile("s_waitcnt vmcnt(8)" ::: "memory");
  __builtin_amdgcn_s_barrier();

  for (int s = 0; s < NS; ++s) {
    int cb = s & 3;
    bf16x8 af[8], bfn[4];
#pragma unroll
    for (int m = 0; m < 8; ++m) af[m] = *(const bf16x8*)&As[cb][offA[m]];
#pragma unroll
    for (int n = 0; n < 4; ++n) bfn[n] = *(const bf16x8*)&Bs[cb][offB[n]];
    int t = s + 3;
    int tb = t & 3;
    if (t > NS - 1) t = NS - 1;
    STAGE256(tb, t);
    __builtin_amdgcn_s_setprio(1);
#pragma unroll
    for (int m = 0; m < 4; ++m)
#pragma unroll
      for (int n = 0; n < 4; ++n) acc[m][n] = mfma16(af[m], bfn[n], acc[m][n]);
    __builtin_amdgcn_s_setprio(0);
    __builtin_amdgcn_s_setprio(1);
#pragma unroll
    for (int m = 4; m < 8; ++m)
#pragma unroll
      for (int n = 0; n < 4; ++n) acc[m][n] = mfma16(af[m], bfn[n], acc[m][n]);
    __builtin_amdgcn_s_setprio(0);
    asm volatile("s_waitcnt vmcnt(8)" ::: "memory");
    __builtin_amdgcn_s_barrier();
  }
#undef STAGE256
  asm volatile("s_waitcnt vmcnt(0)" ::: "memory");

  // C/D layout: col = lane&15, row = (lane>>4)*4 + reg   [measured m89/m91]
  if constexpr (WRITE_VT) {
    if (bcol >= 4096) {
      // V-region block: write transposed to Vt[(b*16+h)*128 + d][t]
      int b_ = (int)(brow >> 11);
      int tb_ = (int)(brow & 2047) + wr * 128;
#pragma unroll
      for (int m = 0; m < 8; ++m)
#pragma unroll
        for (int n = 0; n < 4; ++n) {
          int hd = (int)(bcol - 4096) + wc * 64 + n * 16 + lr;
          int h_ = hd >> 7, d_ = hd & 127;
          U16x4 pk{f2bf(acc[m][n][0]), f2bf(acc[m][n][1]),
                   f2bf(acc[m][n][2]), f2bf(acc[m][n][3])};
          *(U16x4*)(vt + ((long)(b_ * 16 + h_) * 128 + d_) * 2048 + tb_ + m * 16 + lg * 4) = pk;
        }
      return;
    }
  }
#pragma unroll
  for (int m = 0; m < 8; ++m)
#pragma unroll
    for (int n = 0; n < 4; ++n)
#pragma unroll
      for (int r = 0; r < 4; ++r) {
        long row = brow + wr * 128 + m * 16 + lg * 4 + r;
        long col = bcol + wc * 64 + n * 16 + lr;
        float v = acc[m][n][r];
        if constexpr (sizeof(OutT) == 2)
          C[row * N + col] = (OutT)f2bf(v);
        else
          C[row * N + col] = v;
      }
}

// ------------- flash attention v9 (R16-exact, measured): kv-tile 64, 2 blocks/CU ---
// QKV: [8192][6144] bf16 (V third unused); Vt: [64][128][2048] bf16; Y: [8192][2048]
// Grid: x = bh (64), y = 16 (qb = 15 - y). 2 blocks/CU desync naturally (m114).
// Do NOT: 8-wave blocks (R9 +23us), setprio/THR=8 defer-max (R8 +29us, m190),
// kv-tile 32 / 3 blocks/CU (R17: FETCH 3x via L2 thrash + V-swizzle conflicts,
// attn 115->350us).
__global__ __launch_bounds__(256, 2) void k_attn2(const u16* __restrict__ qkv,
                                                  const u16* __restrict__ vt,
                                                  u16* __restrict__ y) {
  __shared__ alignas(16) u16 Ks[2][64 * 128];   // [row t][chunk-swizzled d], 16KB each
  __shared__ alignas(16) u16 Vs[2][128 * 64];   // [row d][chunk-swizzled t], 16KB each

  int bh = blockIdx.x;
  int qb = 15 - (int)blockIdx.y;
  int b = bh >> 4, h = bh & 15;
  int tid = threadIdx.x;
  int lane = tid & 63;
  int w = tid >> 6;
  int lr = lane & 15, lg = lane >> 4;
  int x7 = lr & 7;
  bool hiA = (lane & 32) != 0;   // lg >= 2
  bool hiB = (lane & 16) != 0;   // lg odd
  const float scale2 = 0.08838834764831845f * 1.4426950408889634f;  // /sqrt(128) * log2e

  const u16* kbase = qkv + (long)(b * 2048) * 6144 + 2048 + h * 128;
  const u16* vtbh = vt + (long)bh * 128 * 2048;
  int qbase = qb * 128 + w * 32;

  // Q fragments (B-operand of swapped QK^T): lane lr = q row, lg = d-subgroup
  const u16* qptr = qkv + (long)(qb * 128 + b * 2048) * 6144 + h * 128;
  bf16x8 qf[2][4];
  for (int qsub = 0; qsub < 2; ++qsub)
    for (int dc = 0; dc < 4; ++dc)
      qf[qsub][dc] = *(const bf16x8*)(qptr + (long)(w * 32 + qsub * 16 + lr) * 6144 + dc * 32 + lg * 8);

  f32x4 zero = {0.f, 0.f, 0.f, 0.f};
  f32x4 o[2][8];
  for (int qs = 0; qs < 2; ++qs)
    for (int ds = 0; ds < 8; ++ds) o[qs][ds] = zero;
  float m_run[2] = {-1e30f, -1e30f};   // log2 domain
  float l_run[2] = {0.f, 0.f};

  int nkt = 2 * qb + 2;
  int qmaxw = qbase + 31;

#define STAGE_K(BUF, KT)                                                        \
  do {                                                                          \
    for (int i_ = 0; i_ < 4; ++i_) {                                            \
      int rl_ = w * 16 + i_ * 4;                                                \
      int row_ = rl_ + (lane >> 4);                                             \
      int ch_ = (lane & 15) ^ (row_ & 7);                                       \
      gl16(kbase + (long)((KT)*64 + row_) * 6144 + ch_ * 8, &Ks[BUF][rl_ * 128]); \
    }                                                                           \
  } while (0)

#define STAGE_V(BUF, KT)                                                        \
  do {                                                                          \
    for (int i_ = 0; i_ < 4; ++i_) {                                            \
      int dl_ = w * 32 + i_ * 8;                                                \
      int d_ = dl_ + (lane >> 3);                                               \
      int ch_ = (lane & 7) ^ (d_ & 7);                                          \
      gl16(vtbh + (long)d_ * 2048 + (KT)*64 + ch_ * 8, &Vs[BUF][dl_ * 64]);     \
    }                                                                           \
  } while (0)

// MASKED is a 0/1 literal -> dead branch folds at compile time
#define QKPART(BUF, KT, PA, MASKED)                                             \
  do {                                                                          \
    const u16* Kb = &Ks[BUF][0];                                                \
    f32x4 s[2][4];                                                              \
    for (int qs = 0; qs < 2; ++qs)                                              \
      for (int ks = 0; ks < 4; ++ks) s[qs][ks] = zero;                          \
    for (int ks = 0; ks < 4; ++ks) {                                            \
      int row = ks * 16 + lr;                                                   \
      for (int dc = 0; dc < 4; ++dc) {                                          \
        bf16x8 kf = *(const bf16x8*)(Kb + row * 128 + ((dc * 4 + lg) ^ x7) * 8); \
        s[0][ks] = mfma16(kf, qf[0][dc], s[0][ks]);                             \
        s[1][ks] = mfma16(kf, qf[1][dc], s[1][ks]);                             \
      }                                                                         \
    }                                                                           \
    for (int qs = 0; qs < 2; ++qs) {                                            \
      int qg = qbase + qs * 16 + lr;                                            \
      float p[16];                                                              \
      float tmax = -1e30f;                                                      \
      for (int ks = 0; ks < 4; ++ks)                                            \
        for (int r = 0; r < 4; ++r) {                                           \
          float v = s[qs][ks][r] * scale2;                                      \
          if (MASKED) {                                                         \
            int key = (KT)*64 + ks * 16 + lg * 4 + r;                           \
            v = (key <= qg) ? v : -1e30f;                                       \
          }                                                                     \
          p[ks * 4 + r] = v;                                                    \
          tmax = fmaxf(tmax, v);                                                \
        }                                                                       \
      tmax = fmaxf(tmax, __shfl_xor(tmax, 16));                                 \
      tmax = fmaxf(tmax, __shfl_xor(tmax, 32));                                 \
      /* exact rescale-skip: if tmax <= m_run wave-wide, alpha == 1 exactly */  \
      bool noresc = (__all(tmax <= m_run[qs]) != 0);                            \
      float m_new = noresc ? m_run[qs] : fmaxf(m_run[qs], tmax);                \
      float psum = 0.f;                                                         \
      for (int i = 0; i < 16; ++i) {                                            \
        p[i] = fexp2(p[i] - m_new);                                             \
        psum += p[i];                                                           \
      }                                                                         \
      psum += __shfl_xor(psum, 16);                                             \
      psum += __shfl_xor(psum, 32);                                             \
      if (noresc) {                                                             \
        l_run[qs] = l_run[qs] + psum;                                           \
      } else {                                                                  \
        float alpha = fexp2(m_run[qs] - m_new);                                 \
        l_run[qs] = l_run[qs] * alpha + psum;                                   \
        m_run[qs] = m_new;                                                      \
        float alr[4];                                                           \
        for (int r = 0; r < 4; ++r) alr[r] = __shfl(alpha, lg * 4 + r);         \
        for (int ds = 0; ds < 8; ++ds)                                          \
          for (int r = 0; r < 4; ++r) o[qs][ds][r] *= alr[r];                   \
      }                                                                         \
      /* in-register P regroup (verified R11): 4x4 lg-group transpose of       */ \
      /* bf16-pairs via cvt_pk + xor32/xor16 shuffles                          */ \
      for (int j = 0; j < 2; ++j) {                                             \
        u32 w0 = cvtpk_bf16(p[j * 8 + 0], p[j * 8 + 1]);                        \
        u32 w1 = cvtpk_bf16(p[j * 8 + 2], p[j * 8 + 3]);                        \
        u32 w2 = cvtpk_bf16(p[j * 8 + 4], p[j * 8 + 5]);                        \
        u32 w3 = cvtpk_bf16(p[j * 8 + 6], p[j * 8 + 7]);                        \
        u32 a0 = hiA ? w0 : w2, a1 = hiA ? w1 : w3;                             \
        u32 r0 = __shfl_xor(a0, 32), r1 = __shfl_xor(a1, 32);                   \
        u32 q0 = hiA ? r0 : w0, q1 = hiA ? r1 : w1;                             \
        u32 q2 = hiA ? w2 : r0, q3 = hiA ? w3 : r1;                             \
        u32 s0 = hiB ? q0 : q2, s1 = hiB ? q1 : q3;                             \
        u32 t0 = __shfl_xor(s0, 16), t1 = __shfl_xor(s1, 16);                   \
        u32x4 fw;                                                               \
        fw[0] = hiB ? t0 : q0;                                                  \
        fw[1] = hiB ? t1 : q1;                                                  \
        fw[2] = hiB ? q2 : t0;                                                  \
        fw[3] = hiB ? q3 : t1;                                                  \
        PA[qs][j] = __builtin_bit_cast(bf16x8, fw);                             \
      }                                                                         \
    }                                                                           \
  } while (0)

#define PVPART(BUF, PA)                                                         \
  do {                                                                          \
    const u16* Vb = &Vs[BUF][0];                                                \
    for (int j = 0; j < 2; ++j) {                                               \
      int chv = ((j * 4 + lg) ^ x7) * 8;                                        \
      for (int ds = 0; ds < 8; ++ds) {                                          \
        bf16x8 vf = *(const bf16x8*)(Vb + (ds * 16 + lr) * 64 + chv);           \
        o[0][ds] = mfma16(PA[0][j], vf, o[0][ds]);                              \
        o[1][ds] = mfma16(PA[1][j], vf, o[1][ds]);                              \
      }                                                                         \
    }                                                                           \
  } while (0)

  // prologue: K(0),V(0) staged; land K(0) (own) -> barrier makes it cross-wave;
  // V(0)'s 4 loads remain in flight (matches steady-state counts).
  STAGE_K(0, 0);
  STAGE_V(0, 0);
  asm volatile("s_waitcnt vmcnt(4)" ::: "memory");
  __builtin_amdgcn_s_barrier();

  for (int t = 0; t < nkt; ++t) {
    int tn = (t + 1 < nkt) ? t + 1 : nkt - 1;   // clamped tail keeps counts uniform
    int nb = (t + 1) & 1;
    bool live = (t * 64 <= qmaxw);
    bool masked = (t >= 2 * qb);                // last 2 tiles of the block
    bf16x8 pa[2][2];
    STAGE_K(nb, tn);
    if (live) {
      if (masked) QKPART(t & 1, t, pa, 1);
      else        QKPART(t & 1, t, pa, 0);
    }
    STAGE_V(nb, tn);
    // own V(t) landed (oldest 4 of 12 outstanding); barrier -> cross-wave
    asm volatile("s_waitcnt vmcnt(8)" ::: "memory");
    __builtin_amdgcn_s_barrier();
    if (live) PVPART(t & 1, pa);
    // own K(t+1) landed; V(t+1) stays in flight across the barrier
    asm volatile("s_waitcnt vmcnt(4)" ::: "memory");
    __builtin_amdgcn_s_barrier();
  }
  asm volatile("s_waitcnt vmcnt(0)" ::: "memory");
#undef STAGE_K
#undef STAGE_V
#undef QKPART
#undef PVPART

  float linv[2][4];
  for (int qs = 0; qs < 2; ++qs)
    for (int r = 0; r < 4; ++r) linv[qs][r] = 1.0f / __shfl(l_run[qs], lg * 4 + r);
  u16* yb = y + (long)(b * 2048 + qb * 128 + w * 32) * 2048 + h * 128;
  for (int qs = 0; qs < 2; ++qs)
    for (int ds = 0; ds < 8; ++ds)
      for (int r = 0; r < 4; ++r)
        yb[(long)(qs * 16 + lg * 4 + r) * 2048 + ds * 16 + lr] = f2bf(o[qs][ds][r] * linv[qs][r]);
}

// ------------------------------- launch -------------------------------
extern "C" void kernel_launch(void* const* d_in, const int* in_sizes, int n_in,
                              void* d_out, int out_size, void* d_ws, size_t ws_size,
                              hipStream_t stream) {
  const float* x = (const float*)d_in[0];       // [4,2048,2048]
  const float* w_qkv = (const float*)d_in[1];   // [2048,6144]
  const float* w_proj = (const float*)d_in[2];  // [2048,2048]
  float* out = (float*)d_out;                   // [4,2048,2048] fp32

  char* ws = (char*)d_ws;
  if (ws_size < 201326592ull) return;
  u16* QKV = (u16*)(ws);
  u16* WqT = (u16*)(ws + 100663296);
  u16* WpT = (u16*)(ws + 125829120);
  u16* Xb  = (u16*)(ws + 134217728);
  u16* Vt  = (u16*)(ws + 167772160);

  k_prep<<<6144, 256, 0, stream>>>(x, Xb, w_qkv, WqT, w_proj, WpT);

  // GEMM1 writes Q,K into QKV and V directly transposed into Vt (fused transpose)
  k_gemm256<u16, true><<<dim3(24, 32), 512, 0, stream>>>(Xb, WqT, QKV, Vt, 8192, 6144, 2048);

  k_attn2<<<dim3(64, 16), 256, 0, stream>>>(QKV, Vt, Xb /* Y */);

  k_gemm256<float, false><<<dim3(8, 32), 512, 0, stream>>>(Xb, WpT, out, nullptr, 8192, 2048, 2048);
}

// Round 19
// 393.888 us; speedup vs baseline: 1.5644x; 1.0055x over previous
//
#include <hip/hip_runtime.h>

typedef unsigned short u16;
typedef unsigned int u32;
typedef __bf16 bf16x8 __attribute__((ext_vector_type(8)));
typedef float f32x4 __attribute__((ext_vector_type(4)));
typedef u32 u32x4 __attribute__((ext_vector_type(4)));

__device__ __forceinline__ u16 f2bf(float f) {
  u32 u = __builtin_bit_cast(u32, f);
  return (u16)((u + 0x7fffu + ((u >> 16) & 1u)) >> 16);  // RNE
}

__device__ __forceinline__ f32x4 mfma16(bf16x8 a, bf16x8 b, f32x4 c) {
  return __builtin_amdgcn_mfma_f32_16x16x32_bf16(a, b, c, 0, 0, 0);
}

__device__ __forceinline__ u32 cvtpk_bf16(float lo, float hi) {
  u32 r;
  asm("v_cvt_pk_bf16_f32 %0, %1, %2" : "=v"(r) : "v"(lo), "v"(hi));
  return r;
}

__device__ __forceinline__ float fexp2(float x) {   // raw v_exp_f32 (2^x)
  float r;
  asm("v_exp_f32 %0, %1" : "=v"(r) : "v"(x));
  return r;
}

struct alignas(8) U16x4 { u16 x, y, z, w; };

#define AS1 __attribute__((address_space(1)))
#define AS3 __attribute__((address_space(3)))
// async global->LDS, 16B per lane; lds dest = wave-uniform base + lane*16
__device__ __forceinline__ void gl16(const u16* g, u16* l) {
  __builtin_amdgcn_global_load_lds((const AS1 u32*)g, (AS3 u32*)l, 16, 0, 0);
}

// ---------- fused prep: x fp32->bf16 convert + both weight transposes ----------
__device__ __forceinline__ void transpose_tile(const float* __restrict__ in,
                                               u16* __restrict__ out,
                                               int rows, int cols, int bx, int by,
                                               int tidx) {
  __shared__ float tile[64][65];
  int bc = bx * 64, br = by * 64;
  int tx = tidx & 15;   // float4-col / row-quad index
  int ty = tidx >> 4;   // 0..15
#pragma unroll
  for (int i = 0; i < 4; ++i) {
    int r = ty + i * 16;
    float4 v = *(const float4*)&in[(long)(br + r) * cols + bc + tx * 4];
    tile[r][tx * 4 + 0] = v.x;
    tile[r][tx * 4 + 1] = v.y;
    tile[r][tx * 4 + 2] = v.z;
    tile[r][tx * 4 + 3] = v.w;
  }
  __syncthreads();
#pragma unroll
  for (int i = 0; i < 4; ++i) {
    int c = ty + i * 16;
    int r4 = tx * 4;
    U16x4 o{f2bf(tile[r4 + 0][c]), f2bf(tile[r4 + 1][c]),
            f2bf(tile[r4 + 2][c]), f2bf(tile[r4 + 3][c])};
    *(U16x4*)&out[(long)(bc + c) * rows + br + r4] = o;
  }
}

__global__ __launch_bounds__(256) void k_prep(const float* __restrict__ x,
                                              u16* __restrict__ xb,
                                              const float* __restrict__ wqkv,
                                              u16* __restrict__ wqt,
                                              const float* __restrict__ wproj,
                                              u16* __restrict__ wpt) {
  int bid = blockIdx.x;
  int tid = threadIdx.x;
  if (bid < 2048) {
    long n4 = (8192L * 2048) / 4;
    long i = (long)bid * 256 + tid;
    long stride = 2048L * 256;
    for (; i < n4; i += stride) {
      float4 v = ((const float4*)x)[i];
      U16x4 o{f2bf(v.x), f2bf(v.y), f2bf(v.z), f2bf(v.w)};
      ((U16x4*)xb)[i] = o;
    }
  } else if (bid < 5120) {
    int idx = bid - 2048;                      // 96 x 32 tiles
    transpose_tile(wqkv, wqt, 2048, 6144, idx % 96, idx / 96, tid);
  } else {
    int idx = bid - 5120;                      // 32 x 32 tiles
    transpose_tile(wproj, wpt, 2048, 2048, idx % 32, idx / 32, tid);
  }
}

// ------------- GEMM 256x256: C[M][N] = A[M][K](bf16) @ Bt[N][K](bf16)^T -------------
// R6-exact K-loop (measured 11x: 185-191us GEMM1, MfmaUtil 50-52%, 0 conflicts).
// Failed refinements, do not retry: R7 coarse 2-phase split (-29%, m196);
// R10 ping-pong register prefetch (-30%); 8-phase ledger rederivation converges
// to R7's structure -> frozen. BK=64 2-deep forces vmcnt(0) drain (m97 pattern)
// and 3+-deep exceeds 160KB LDS -> BK=32/4-deep is the unique point.
// WRITE_VT epilogue (R14, verified): V-region blocks (bcol>=4096) write
// transposed directly to Vt[bh][d][t], replacing k_transpose_v.
template <typename OutT, bool WRITE_VT>
__global__ __launch_bounds__(512, 2) void k_gemm256(const u16* __restrict__ A,
                                                    const u16* __restrict__ Bt,
                                                    OutT* __restrict__ C,
                                                    u16* __restrict__ vt,
                                                    int M, int N, int K) {
  __shared__ alignas(16) u16 As[4][8192];  // 4 x 16KB
  __shared__ alignas(16) u16 Bs[4][8192];  // 4 x 16KB  (total 128KB)

  int gx = gridDim.x;
  int nwg = gx * gridDim.y;
  int bid = blockIdx.y * gx + blockIdx.x;
  int swz = (bid & 7) * (nwg >> 3) + (bid >> 3);
  int rem = swz % (gx * 4);
  int bx = rem >> 2;
  int by = (swz / (gx * 4)) * 4 + (rem & 3);

  int tid = threadIdx.x;
  int lane = tid & 63;
  int w = tid >> 6;
  int wr = w >> 2, wc = w & 3;     // wave tile: rows wr*128+[0,128), cols wc*64+[0,64)
  int lr = lane & 15, lg = lane >> 4;
  long brow = (long)by * 256, bcol = (long)bx * 256;

  int rS[2], cS[2];
#pragma unroll
  for (int i = 0; i < 2; ++i) {
    int q = i * 512 + tid;
    rS[i] = q >> 2;                                 // tile row (0..255)
    cS[i] = ((q & 3) ^ ((rS[i] >> 1) & 3)) << 3;    // swizzled source k-chunk (u16 off)
  }
  const u16* Ab = A + brow * K;
  const u16* Bb = Bt + bcol * K;

  int offA[8], offB[4];
#pragma unroll
  for (int m = 0; m < 8; ++m) {
    int row = wr * 128 + m * 16 + lr;
    offA[m] = row * 32 + ((lg ^ ((row >> 1) & 3)) << 3);
  }
#pragma unroll
  for (int n = 0; n < 4; ++n) {
    int row = wc * 64 + n * 16 + lr;
    offB[n] = row * 32 + ((lg ^ ((row >> 1) & 3)) << 3);
  }

  f32x4 zero = {0.f, 0.f, 0.f, 0.f};
  f32x4 acc[8][4];
#pragma unroll
  for (int m = 0; m < 8; ++m)
#pragma unroll
    for (int n = 0; n < 4; ++n) acc[m][n] = zero;

  int NS = K >> 5;  // K-steps (64 for K=2048)

#define STAGE256(SBUF, KT)                                                          \
  do {                                                                              \
    int kk_ = (KT) << 5;                                                            \
    gl16(Ab + (long)rS[0] * K + kk_ + cS[0], &As[SBUF][(0 * 512 + w * 64) * 8]);    \
    gl16(Ab + (long)rS[1] * K + kk_ + cS[1], &As[SBUF][(1 * 512 + w * 64) * 8]);    \
    gl16(Bb + (long)rS[0] * K + kk_ + cS[0], &Bs[SBUF][(0 * 512 + w * 64) * 8]);    \
    gl16(Bb + (long)rS[1] * K + kk_ + cS[1], &Bs[SBUF][(1 * 512 + w * 64) * 8]);    \
  } while (0)

  STAGE256(0, 0);
  STAGE256(1, 1);
  STAGE256(2, 2);
  asm volatile("s_waitcnt vmcnt(8)" ::: "memory");
  __builtin_amdgcn_s_barrier();

  for (int s = 0; s < NS; ++s) {
    int cb = s & 3;
    bf16x8 af[8], bfn[4];
#pragma unroll
    for (int m = 0; m < 8; ++m) af[m] = *(const bf16x8*)&As[cb][offA[m]];
#pragma unroll
    for (int n = 0; n < 4; ++n) bfn[n] = *(const bf16x8*)&Bs[cb][offB[n]];
    int t = s + 3;
    int tb = t & 3;
    if (t > NS - 1) t = NS - 1;
    STAGE256(tb, t);
    __builtin_amdgcn_s_setprio(1);
#pragma unroll
    for (int m = 0; m < 4; ++m)
#pragma unroll
      for (int n = 0; n < 4; ++n) acc[m][n] = mfma16(af[m], bfn[n], acc[m][n]);
    __builtin_amdgcn_s_setprio(0);
    __builtin_amdgcn_s_setprio(1);
#pragma unroll
    for (int m = 4; m < 8; ++m)
#pragma unroll
      for (int n = 0; n < 4; ++n) acc[m][n] = mfma16(af[m], bfn[n], acc[m][n]);
    __builtin_amdgcn_s_setprio(0);
    asm volatile("s_waitcnt vmcnt(8)" ::: "memory");
    __builtin_amdgcn_s_barrier();
  }
#undef STAGE256
  asm volatile("s_waitcnt vmcnt(0)" ::: "memory");

  // C/D layout: col = lane&15, row = (lane>>4)*4 + reg   [measured m89/m91]
  if constexpr (WRITE_VT) {
    if (bcol >= 4096) {
      // V-region block: write transposed to Vt[(b*16+h)*128 + d][t]
      int b_ = (int)(brow >> 11);
      int tb_ = (int)(brow & 2047) + wr * 128;
#pragma unroll
      for (int m = 0; m < 8; ++m)
#pragma unroll
        for (int n = 0; n < 4; ++n) {
          int hd = (int)(bcol - 4096) + wc * 64 + n * 16 + lr;
          int h_ = hd >> 7, d_ = hd & 127;
          U16x4 pk{f2bf(acc[m][n][0]), f2bf(acc[m][n][1]),
                   f2bf(acc[m][n][2]), f2bf(acc[m][n][3])};
          *(U16x4*)(vt + ((long)(b_ * 16 + h_) * 128 + d_) * 2048 + tb_ + m * 16 + lg * 4) = pk;
        }
      return;
    }
  }
#pragma unroll
  for (int m = 0; m < 8; ++m)
#pragma unroll
    for (int n = 0; n < 4; ++n)
#pragma unroll
      for (int r = 0; r < 4; ++r) {
        long row = brow + wr * 128 + m * 16 + lg * 4 + r;
        long col = bcol + wc * 64 + n * 16 + lr;
        float v = acc[m][n][r];
        if constexpr (sizeof(OutT) == 2)
          C[row * N + col] = (OutT)f2bf(v);
        else
          C[row * N + col] = v;
      }
}

// ------------- flash attention v11: deferred l-reduction (epilogue-only) -------
// QKV: [8192][6144] bf16 (V third unused); Vt: [64][128][2048] bf16; Y: [8192][2048]
// Grid: x = bh (64), y = 16 (qb = 15 - y). 2 blocks/CU desync naturally (m114).
// Do NOT: 8-wave blocks (R9 +23us), setprio/THR=8 defer-max (R8 +29us, m190),
// kv-tile 32 / 3 blocks/CU (R17: FETCH 3x L2 thrash + V-swizzle conflicts).
// NEW: l_run kept LANE-PARTIAL (no per-tile psum shuffles). Valid because after
// the tmax reduce, m_run (hence alpha) is uniform across the 4 lanes of a q-row,
// so partial sums rescale identically. Single xor16+xor32 reduce in epilogue.
__global__ __launch_bounds__(256, 2) void k_attn2(const u16* __restrict__ qkv,
                                                  const u16* __restrict__ vt,
                                                  u16* __restrict__ y) {
  __shared__ alignas(16) u16 Ks[2][64 * 128];   // [row t][chunk-swizzled d], 16KB each
  __shared__ alignas(16) u16 Vs[2][128 * 64];   // [row d][chunk-swizzled t], 16KB each

  int bh = blockIdx.x;
  int qb = 15 - (int)blockIdx.y;
  int b = bh >> 4, h = bh & 15;
  int tid = threadIdx.x;
  int lane = tid & 63;
  int w = tid >> 6;
  int lr = lane & 15, lg = lane >> 4;
  int x7 = lr & 7;
  bool hiA = (lane & 32) != 0;   // lg >= 2
  bool hiB = (lane & 16) != 0;   // lg odd
  const float scale2 = 0.08838834764831845f * 1.4426950408889634f;  // /sqrt(128) * log2e

  const u16* kbase = qkv + (long)(b * 2048) * 6144 + 2048 + h * 128;
  const u16* vtbh = vt + (long)bh * 128 * 2048;
  int qbase = qb * 128 + w * 32;

  // Q fragments (B-operand of swapped QK^T): lane lr = q row, lg = d-subgroup
  const u16* qptr = qkv + (long)(qb * 128 + b * 2048) * 6144 + h * 128;
  bf16x8 qf[2][4];
  for (int qsub = 0; qsub < 2; ++qsub)
    for (int dc = 0; dc < 4; ++dc)
      qf[qsub][dc] = *(const bf16x8*)(qptr + (long)(w * 32 + qsub * 16 + lr) * 6144 + dc * 32 + lg * 8);

  f32x4 zero = {0.f, 0.f, 0.f, 0.f};
  f32x4 o[2][8];
  for (int qs = 0; qs < 2; ++qs)
    for (int ds = 0; ds < 8; ++ds) o[qs][ds] = zero;
  float m_run[2] = {-1e30f, -1e30f};   // log2 domain
  float l_run[2] = {0.f, 0.f};         // LANE-PARTIAL (reduced in epilogue)

  int nkt = 2 * qb + 2;
  int qmaxw = qbase + 31;

#define STAGE_K(BUF, KT)                                                        \
  do {                                                                          \
    for (int i_ = 0; i_ < 4; ++i_) {                                            \
      int rl_ = w * 16 + i_ * 4;                                                \
      int row_ = rl_ + (lane >> 4);                                             \
      int ch_ = (lane & 15) ^ (row_ & 7);                                       \
      gl16(kbase + (long)((KT)*64 + row_) * 6144 + ch_ * 8, &Ks[BUF][rl_ * 128]); \
    }                                                                           \
  } while (0)

#define STAGE_V(BUF, KT)                                                        \
  do {                                                                          \
    for (int i_ = 0; i_ < 4; ++i_) {                                            \
      int dl_ = w * 32 + i_ * 8;                                                \
      int d_ = dl_ + (lane >> 3);                                               \
      int ch_ = (lane & 7) ^ (d_ & 7);                                          \
      gl16(vtbh + (long)d_ * 2048 + (KT)*64 + ch_ * 8, &Vs[BUF][dl_ * 64]);     \
    }                                                                           \
  } while (0)

// MASKED is a 0/1 literal -> dead branch folds at compile time
#define QKPART(BUF, KT, PA, MASKED)                                             \
  do {                                                                          \
    const u16* Kb = &Ks[BUF][0];                                                \
    f32x4 s[2][4];                                                              \
    for (int qs = 0; qs < 2; ++qs)                                              \
      for (int ks = 0; ks < 4; ++ks) s[qs][ks] = zero;                          \
    for (int ks = 0; ks < 4; ++ks) {                                            \
      int row = ks * 16 + lr;                                                   \
      for (int dc = 0; dc < 4; ++dc) {                                          \
        bf16x8 kf = *(const bf16x8*)(Kb + row * 128 + ((dc * 4 + lg) ^ x7) * 8); \
        s[0][ks] = mfma16(kf, qf[0][dc], s[0][ks]);                             \
        s[1][ks] = mfma16(kf, qf[1][dc], s[1][ks]);                             \
      }                                                                         \
    }                                                                           \
    for (int qs = 0; qs < 2; ++qs) {                                            \
      int qg = qbase + qs * 16 + lr;                                            \
      float p[16];                                                              \
      float tmax = -1e30f;                                                      \
      for (int ks = 0; ks < 4; ++ks)                                            \
        for (int r = 0; r < 4; ++r) {                                           \
          float v = s[qs][ks][r] * scale2;                                      \
          if (MASKED) {                                                         \
            int key = (KT)*64 + ks * 16 + lg * 4 + r;                           \
            v = (key <= qg) ? v : -1e30f;                                       \
          }                                                                     \
          p[ks * 4 + r] = v;                                                    \
          tmax = fmaxf(tmax, v);                                                \
        }                                                                       \
      tmax = fmaxf(tmax, __shfl_xor(tmax, 16));                                 \
      tmax = fmaxf(tmax, __shfl_xor(tmax, 32));                                 \
      /* exact rescale-skip: if tmax <= m_run wave-wide, alpha == 1 exactly */  \
      bool noresc = (__all(tmax <= m_run[qs]) != 0);                            \
      float m_new = noresc ? m_run[qs] : fmaxf(m_run[qs], tmax);                \
      float psum = 0.f;                                                         \
      for (int i = 0; i < 16; ++i) {                                            \
        p[i] = fexp2(p[i] - m_new);                                             \
        psum += p[i];                                                           \
      }                                                                         \
      /* l_run stays lane-partial: no cross-lane psum reduce here */            \
      if (noresc) {                                                             \
        l_run[qs] = l_run[qs] + psum;                                           \
      } else {                                                                  \
        float alpha = fexp2(m_run[qs] - m_new);                                 \
        l_run[qs] = l_run[qs] * alpha + psum;                                   \
        m_run[qs] = m_new;                                                      \
        float alr[4];                                                           \
        for (int r = 0; r < 4; ++r) alr[r] = __shfl(alpha, lg * 4 + r);         \
        for (int ds = 0; ds < 8; ++ds)                                          \
          for (int r = 0; r < 4; ++r) o[qs][ds][r] *= alr[r];                   \
      }                                                                         \
      /* in-register P regroup (verified R11): 4x4 lg-group transpose of       */ \
      /* bf16-pairs via cvt_pk + xor32/xor16 shuffles                          */ \
      for (int j = 0; j < 2; ++j) {                                             \
        u32 w0 = cvtpk_bf16(p[j * 8 + 0], p[j * 8 + 1]);                        \
        u32 w1 = cvtpk_bf16(p[j * 8 + 2], p[j * 8 + 3]);                        \
        u32 w2 = cvtpk_bf16(p[j * 8 + 4], p[j * 8 + 5]);                        \
        u32 w3 = cvtpk_bf16(p[j * 8 + 6], p[j * 8 + 7]);                        \
        u32 a0 = hiA ? w0 : w2, a1 = hiA ? w1 : w3;                             \
        u32 r0 = __shfl_xor(a0, 32), r1 = __shfl_xor(a1, 32);                   \
        u32 q0 = hiA ? r0 : w0, q1 = hiA ? r1 : w1;                             \
        u32 q2 = hiA ? w2 : r0, q3 = hiA ? w3 : r1;                             \
        u32 s0 = hiB ? q0 : q2, s1 = hiB ? q1 : q3;                             \
        u32 t0 = __shfl_xor(s0, 16), t1 = __shfl_xor(s1, 16);                   \
        u32x4 fw;                                                               \
        fw[0] = hiB ? t0 : q0;                                                  \
        fw[1] = hiB ? t1 : q1;                                                  \
        fw[2] = hiB ? q2 : t0;                                                  \
        fw[3] = hiB ? q3 : t1;                                                  \
        PA[qs][j] = __builtin_bit_cast(bf16x8, fw);                             \
      }                                                                         \
    }                                                                           \
  } while (0)

#define PVPART(BUF, PA)                                                         \
  do {                                                                          \
    const u16* Vb = &Vs[BUF][0];                                                \
    for (int j = 0; j < 2; ++j) {                                               \
      int chv = ((j * 4 + lg) ^ x7) * 8;                                        \
      for (int ds = 0; ds < 8; ++ds) {                                          \
        bf16x8 vf = *(const bf16x8*)(Vb + (ds * 16 + lr) * 64 + chv);           \
        o[0][ds] = mfma16(PA[0][j], vf, o[0][ds]);                              \
        o[1][ds] = mfma16(PA[1][j], vf, o[1][ds]);                              \
      }                                                                         \
    }                                                                           \
  } while (0)

  // prologue: K(0),V(0) staged; land K(0) (own) -> barrier makes it cross-wave;
  // V(0)'s 4 loads remain in flight (matches steady-state counts).
  STAGE_K(0, 0);
  STAGE_V(0, 0);
  asm volatile("s_waitcnt vmcnt(4)" ::: "memory");
  __builtin_amdgcn_s_barrier();

  for (int t = 0; t < nkt; ++t) {
    int tn = (t + 1 < nkt) ? t + 1 : nkt - 1;   // clamped tail keeps counts uniform
    int nb = (t + 1) & 1;
    bool live = (t * 64 <= qmaxw);
    bool masked = (t >= 2 * qb);                // last 2 tiles of the block
    bf16x8 pa[2][2];
    STAGE_K(nb, tn);
    if (live) {
      if (masked) QKPART(t & 1, t, pa, 1);
      else        QKPART(t & 1, t, pa, 0);
    }
    STAGE_V(nb, tn);
    // own V(t) landed (oldest 4 of 12 outstanding); barrier -> cross-wave
    asm volatile("s_waitcnt vmcnt(8)" ::: "memory");
    __builtin_amdgcn_s_barrier();
    if (live) PVPART(t & 1, pa);
    // own K(t+1) landed; V(t+1) stays in flight across the barrier
    asm volatile("s_waitcnt vmcnt(4)" ::: "memory");
    __builtin_amdgcn_s_barrier();
  }
  asm volatile("s_waitcnt vmcnt(0)" ::: "memory");
#undef STAGE_K
#undef STAGE_V
#undef QKPART
#undef PVPART

  // epilogue: single cross-lane l reduction (was per-tile), then broadcast
  float linv[2][4];
  for (int qs = 0; qs < 2; ++qs) {
    float lv = l_run[qs];
    lv += __shfl_xor(lv, 16);
    lv += __shfl_xor(lv, 32);
    for (int r = 0; r < 4; ++r) linv[qs][r] = 1.0f / __shfl(lv, lg * 4 + r);
  }
  u16* yb = y + (long)(b * 2048 + qb * 128 + w * 32) * 2048 + h * 128;
  for (int qs = 0; qs < 2; ++qs)
    for (int ds = 0; ds < 8; ++ds)
      for (int r = 0; r < 4; ++r)
        yb[(long)(qs * 16 + lg * 4 + r) * 2048 + ds * 16 + lr] = f2bf(o[qs][ds][r] * linv[qs][r]);
}

// ------------------------------- launch -------------------------------
extern "C" void kernel_launch(void* const* d_in, const int* in_sizes, int n_in,
                              void* d_out, int out_size, void* d_ws, size_t ws_size,
                              hipStream_t stream) {
  const float* x = (const float*)d_in[0];       // [4,2048,2048]
  const float* w_qkv = (const float*)d_in[1];   // [2048,6144]
  const float* w_proj = (const float*)d_in[2];  // [2048,2048]
  float* out = (float*)d_out;                   // [4,2048,2048] fp32

  char* ws = (char*)d_ws;
  if (ws_size < 201326592ull) return;
  u16* QKV = (u16*)(ws);
  u16* WqT = (u16*)(ws + 100663296);
  u16* WpT = (u16*)(ws + 125829120);
  u16* Xb  = (u16*)(ws + 134217728);
  u16* Vt  = (u16*)(ws + 167772160);

  k_prep<<<6144, 256, 0, stream>>>(x, Xb, w_qkv, WqT, w_proj, WpT);

  // GEMM1 writes Q,K into QKV and V directly transposed into Vt (fused transpose)
  k_gemm256<u16, true><<<dim3(24, 32), 512, 0, stream>>>(Xb, WqT, QKV, Vt, 8192, 6144, 2048);

  k_attn2<<<dim3(64, 16), 256, 0, stream>>>(QKV, Vt, Xb /* Y */);

  k_gemm256<float, false><<<dim3(8, 32), 512, 0, stream>>>(Xb, WpT, out, nullptr, 8192, 2048, 2048);
}